// Round 15
// baseline (75.785 us; speedup 1.0000x reference)
//
#include <hip/hip_runtime.h>
#include <stdint.h>

typedef float  f32x4  __attribute__((ext_vector_type(4)));
typedef short  bf16x8 __attribute__((ext_vector_type(8)));
typedef int    i32x4  __attribute__((ext_vector_type(4)));

#define C1f 0.70710678118654752f
#define C2f 0.5f
#define C3f 0.35355339059327373f

#define NT 512          // 8 waves
#define CH 16           // chunk rows
#define RBF 2064        // f32 LDS row stride bytes (2048 + 16 pad -> bank skew 4)
#define CHSZ (CH*RBF)   // 33024 B
#define NBUF 4          // 132096 B total
#define RPB 256         // rows per block
#define NCHUNK (RPB/CH) // 16

__device__ __forceinline__ unsigned int f2b(float f) {
    unsigned int u; __builtin_memcpy(&u, &f, 4);
    u += 0x7fffu + ((u >> 16) & 1u);          // RTNE f32 -> bf16
    return u >> 16;
}
__device__ __forceinline__ unsigned int pack2(float lo, float hi) {
    return f2b(lo) | (f2b(hi) << 16);
}
__device__ __forceinline__ bf16x8 cast8(i32x4 v) {
    bf16x8 r; __builtin_memcpy(&r, &v, 16); return r;
}
// packed f32->bf16 (RTNE), 1 inst per pair
__device__ __forceinline__ unsigned int cvtpk(float lo, float hi) {
    unsigned int r;
    asm("v_cvt_pk_bf16_f32 %0, %1, %2" : "=v"(r) : "v"(lo), "v"(hi));
    return r;
}

// LDS-only barrier: orders ds ops across the workgroup WITHOUT draining vmcnt.
__device__ __forceinline__ void lds_barrier() {
    asm volatile("s_waitcnt lgkmcnt(0)" ::: "memory");
    __builtin_amdgcn_s_barrier();
    __builtin_amdgcn_sched_barrier(0);
}
__device__ __forceinline__ void vwait4() { asm volatile("s_waitcnt vmcnt(4)" ::: "memory"); __builtin_amdgcn_sched_barrier(0); }
__device__ __forceinline__ void vwait6() { asm volatile("s_waitcnt vmcnt(6)" ::: "memory"); __builtin_amdgcn_sched_barrier(0); }
__device__ __forceinline__ void vwait8() { asm volatile("s_waitcnt vmcnt(8)" ::: "memory"); __builtin_amdgcn_sched_barrier(0); }

// async global->LDS, 16B per lane (dest = wave-uniform base + lane*16)
__device__ __forceinline__ void gld_lds16(const float* g, char* l) {
    __builtin_amdgcn_global_load_lds((const unsigned int*)g, (unsigned int*)l, 16, 0, 0);
}

// G[o][i0..i0+7] as bf16x8.  G = composed DWT -> blockdiag(W) -> IDWT matrix:
// G[o][i] = 1/8*Wa[o/8][i/8] + 1/8*s2(o)s2(i)*W2[o/8][i/8]
//         + 1/4*s1(o)s1(i)*W1[o/4][i/4] + 1/2*s0(o)s0(i)*W0[o/2][i/2]
__device__ __forceinline__ bf16x8 g_frag(int o, int i0,
        const float* __restrict__ W0, const float* __restrict__ W1,
        const float* __restrict__ W2, const float* __restrict__ Wa)
{
    const float s0o = (o & 1) ? -1.f : 1.f;
    const float s1o = ((o >> 1) & 1) ? -1.f : 1.f;
    const float s2o = ((o >> 2) & 1) ? -1.f : 1.f;
    const float4 w0 = *(const float4*)(W0 + (o >> 1) * 256 + (i0 >> 1));
    const float2 w1 = *(const float2*)(W1 + (o >> 2) * 128 + (i0 >> 2));
    const float  w2 = W2[(o >> 3) * 64 + (i0 >> 3)];
    const float  wa = Wa[(o >> 3) * 64 + (i0 >> 3)];
    const float base = 0.125f * wa;
    const float c2   = 0.125f * s2o * w2;
    const float c1   = 0.25f  * s1o;
    const float c0   = 0.5f   * s0o;
    const float w0a[4] = { w0.x, w0.y, w0.z, w0.w };
    const float w1a[2] = { w1.x, w1.y };
    float g[8];
    #pragma unroll
    for (int e = 0; e < 8; ++e) {
        const float t2 = ((e >> 2) & 1) ? -c2 : c2;
        const float t1 = (((e >> 1) & 1) ? -c1 : c1) * w1a[e >> 2];
        const float t0 = ((e & 1) ? -c0 : c0) * w0a[e >> 1];
        g[e] = base + t2 + t1 + t0;
    }
    i32x4 p = { (int)pack2(g[0],g[1]), (int)pack2(g[2],g[3]),
                (int)pack2(g[4],g[5]), (int)pack2(g[6],g[7]) };
    return cast8(p);
}

// prep: build G in MFMA-fragment blob order + bias vector g.
__global__ void prep(const float* __restrict__ W0, const float* __restrict__ b0,
                     const float* __restrict__ W1, const float* __restrict__ b1,
                     const float* __restrict__ W2, const float* __restrict__ b2,
                     const float* __restrict__ Wa, const float* __restrict__ ba,
                     unsigned short* __restrict__ ws)
{
    const int gid  = blockIdx.x * 256 + threadIdx.x;   // 32768 threads
    const int blob = gid >> 6, lane = gid & 63;
    const int otg  = blob >> 4, ks = blob & 15;
    const int o  = otg * 16 + (lane & 15);
    const int i0 = ks * 32 + ((lane >> 4) * 8);
    bf16x8 f = g_frag(o, i0, W0, W1, W2, Wa);
    i32x4 p; __builtin_memcpy(&p, &f, 16);
    *(i32x4*)(ws + blob * 512 + lane * 8) = p;
    if (gid < 512) {
        float* gv = (float*)(ws + 262144);
        const int oo = gid;
        const float s0 = (oo & 1) ? -C1f : C1f;
        const float s1 = ((oo >> 1) & 1) ? -C2f : C2f;
        const float s2 = ((oo >> 2) & 1) ? -C3f : C3f;
        gv[oo] = C3f * ba[oo >> 3] + s2 * b2[oo >> 3] + s1 * b1[oo >> 2] + s0 * b0[oo >> 1];
    }
}

// main: out = x @ G^T + g.  Block: 256 rows x 256 cols (col-half), 8 waves.
// Wave owns TWO 16-col tiles (B = 128 regs, loaded once).  x streams as f32 via
// global_load_lds DMA into 4 x 16-row LDS buffers (depth-2 prefetch, counted
// vmcnt, lgkm-only barriers) -> HBM queue never drains across barriers.
// Fragments convert f32->bf16 at read time via v_cvt_pk_bf16_f32.
template<int USE_WS>
__global__ __launch_bounds__(NT, 2)
void wavelet_gemm(const float* __restrict__ x,
                  const float* __restrict__ W0, const float* __restrict__ b0,
                  const float* __restrict__ W1, const float* __restrict__ b1,
                  const float* __restrict__ W2, const float* __restrict__ b2,
                  const float* __restrict__ Wa, const float* __restrict__ ba,
                  const unsigned short* __restrict__ wsb,
                  float* __restrict__ out, int nblk)
{
    __shared__ char lds[NBUF * CHSZ];     // 132096 B

    const int tid  = threadIdx.x;
    const int lane = tid & 63;
    const int wave = tid >> 6;            // 0..7

    // XCD-chunked bijective swizzle (nblk % 8 == 0); chalf fastest-varying so the
    // two col-halves of the same rows are XCD-adjacent (x shared via L2).
    const int cpx = nblk >> 3;
    const int lbid = ((int)blockIdx.x & 7) * cpx + ((int)blockIdx.x >> 3);
    const int chalf = lbid & 1;
    const long rowblk = (long)(lbid >> 1) * RPB;

    const int otg0 = chalf * 16 + wave * 2;   // first of two col-tiles
    const int col0 = otg0 * 16;
    const int bc0  = col0 + ((lane >> 4) << 2);   // lane's 4 cols in tile 0

    // ---- B: two col-tiles' full-K G fragments, loaded once (128 regs) ----
    bf16x8 B0[16], B1[16];
    if (USE_WS) {
        #pragma unroll
        for (int ks = 0; ks < 16; ++ks) {
            B0[ks] = cast8(*(const i32x4*)(wsb + ((size_t)(otg0 * 16 + ks) * 512) + lane * 8));
            B1[ks] = cast8(*(const i32x4*)(wsb + ((size_t)((otg0 + 1) * 16 + ks) * 512) + lane * 8));
        }
    } else {
        #pragma unroll
        for (int ks = 0; ks < 16; ++ks) {
            B0[ks] = g_frag(col0 + (lane & 15),      ks * 32 + ((lane >> 4) * 8), W0, W1, W2, Wa);
            B1[ks] = g_frag(col0 + 16 + (lane & 15), ks * 32 + ((lane >> 4) * 8), W0, W1, W2, Wa);
        }
    }
    #pragma unroll
    for (int ks = 0; ks < 16; ++ks) {     // pin: no re-issue inside the loop
        i32x4 t0, t1;
        __builtin_memcpy(&t0, &B0[ks], 16);
        __builtin_memcpy(&t1, &B1[ks], 16);
        asm volatile("" : "+v"(t0), "+v"(t1));
        __builtin_memcpy(&B0[ks], &t0, 16);
        __builtin_memcpy(&B1[ks], &t1, 16);
    }

    // bias for this lane's 4 cols in each tile
    f32x4 gv40, gv41;
    if (USE_WS) {
        const float4 g0 = *(const float4*)((const float*)(wsb + 262144) + bc0);
        const float4 g1 = *(const float4*)((const float*)(wsb + 262144) + bc0 + 16);
        gv40 = f32x4{ g0.x, g0.y, g0.z, g0.w };
        gv41 = f32x4{ g1.x, g1.y, g1.z, g1.w };
    } else {
        #pragma unroll
        for (int j = 0; j < 4; ++j) {
            #pragma unroll
            for (int t = 0; t < 2; ++t) {
                const int col = bc0 + t * 16 + j;
                const float s0 = (col & 1) ? -C1f : C1f;
                const float s1 = ((col >> 1) & 1) ? -C2f : C2f;
                const float s2 = ((col >> 2) & 1) ? -C3f : C3f;
                const float v = C3f * ba[col >> 3] + s2 * b2[col >> 3] + s1 * b1[col >> 2] + s0 * b0[col >> 1];
                if (t == 0) gv40[j] = v; else gv41[j] = v;
            }
        }
    }

    // stage chunk c via DMA: 16 rows x 2KB f32; wave w covers rows 2w..2w+1,
    // 2 DMA per row (1KB each, lane*16B).  4 DMA per wave per chunk.
    auto stage = [&](int c) {
        char* base = lds + (c & (NBUF - 1)) * CHSZ;
        const float* xc = x + (rowblk + (long)c * CH) * 512;
        #pragma unroll
        for (int i = 0; i < 2; ++i) {
            const int r = wave * 2 + i;
            const float* gp = xc + (long)r * 512 + lane * 4;
            char* lp = base + r * RBF;
            gld_lds16(gp, lp);
            gld_lds16(gp + 256, lp + 1024);
        }
        __builtin_amdgcn_sched_barrier(0);
    };
    // compute one 16-row chunk: 16 ks; fragment = 2x ds_read_b128 f32 + 4 cvt_pk;
    // each A feeds 2 MFMAs.  Ends with 2 f32x4 out-stores.
    auto compute = [&](int c) {
        const char* pa = lds + (c & (NBUF - 1)) * CHSZ + (lane & 15) * RBF + ((lane >> 4) * 32);
        f32x4 acc0 = {}, acc1 = {};
        #pragma unroll
        for (int ks = 0; ks < 16; ++ks) {
            f32x4 lo = *(const f32x4*)(pa + ks * 128);
            f32x4 hi = *(const f32x4*)(pa + ks * 128 + 16);
            i32x4 pk = { (int)cvtpk(lo[0], lo[1]), (int)cvtpk(lo[2], lo[3]),
                         (int)cvtpk(hi[0], hi[1]), (int)cvtpk(hi[2], hi[3]) };
            bf16x8 a = cast8(pk);
            acc0 = __builtin_amdgcn_mfma_f32_16x16x32_bf16(B0[ks], a, acc0, 0, 0, 0);
            acc1 = __builtin_amdgcn_mfma_f32_16x16x32_bf16(B1[ks], a, acc1, 0, 0, 0);
        }
        const long rr = (rowblk + (long)c * CH + (lane & 15)) * 512;
        *(f32x4*)(out + rr + bc0)      = acc0 + gv40;
        *(f32x4*)(out + rr + bc0 + 16) = acc1 + gv41;
    };

    // ---- prologue: queue chunks 0 and 1 ----
    stage(0);
    stage(1);
    vwait4();         // DMA(0) done (4 newer = DMA(1) still in flight)
    lds_barrier();

    // ---- main loop: depth-2 DMA pipeline ----
    // per-wave vmem issue order: ... DMA(c+1)[4], st(c-1)[2], DMA(c+2)[4], st(c)[2]
    // wait for DMA(c+1): newer = st(c-1)+DMA(c+2)+st(c) = 8 (6 at c==0; 4 at tail)
    #pragma unroll 1
    for (int c = 0; c < NCHUNK; ++c) {
        if (c + 2 < NCHUNK) stage(c + 2);
        compute(c);
        if (c + 2 < NCHUNK) {
            if (c == 0) vwait6(); else vwait8();
            lds_barrier();
        } else if (c + 1 < NCHUNK) {
            vwait4();
            lds_barrier();
        }
    }
}

extern "C" void kernel_launch(void* const* d_in, const int* in_sizes, int n_in,
                              void* d_out, int out_size, void* d_ws, size_t ws_size,
                              hipStream_t stream)
{
    const float* x  = (const float*)d_in[0];
    const float* W0 = (const float*)d_in[1];
    const float* b0 = (const float*)d_in[2];
    const float* W1 = (const float*)d_in[3];
    const float* b1 = (const float*)d_in[4];
    const float* W2 = (const float*)d_in[5];
    const float* b2 = (const float*)d_in[6];
    const float* Wa = (const float*)d_in[7];
    const float* ba = (const float*)d_in[8];
    float* out = (float*)d_out;

    const int nrows = in_sizes[0] / 512;      // 65536
    const int nblk  = (nrows / RPB) * 2;      // 512 (row-groups x col-halves)

    if (ws_size >= (size_t)(524288 + 2048)) {
        unsigned short* ws = (unsigned short*)d_ws;
        prep<<<128, 256, 0, stream>>>(W0, b0, W1, b1, W2, b2, Wa, ba, ws);
        wavelet_gemm<1><<<nblk, NT, 0, stream>>>(x, W0, b0, W1, b1, W2, b2, Wa, ba, ws, out, nblk);
    } else {
        wavelet_gemm<0><<<nblk, NT, 0, stream>>>(x, W0, b0, W1, b1, W2, b2, Wa, ba, nullptr, out, nblk);
    }
}